// Round 6
// baseline (98.296 us; speedup 1.0000x reference)
//
#include <hip/hip_runtime.h>
#include <math.h>

#define OUT_H 7
#define OUT_W 7
#define NBINS 49
#define CPB 4   // channels per block = waves per block

// Fused RoI max-pool, original (B,C,H,W) layout. Key fact: W == 64 == wave
// size, so lane==x makes every feature-row load one coalesced 256B vector op.
// Block = 4 waves = 4 channels of one ROI; all control flow block-uniform.
// Bin bounds: exact integer floor(k*roi/7) == (k*roi)/7 (validated R4,
// absmax 0 vs the f64 numpy reference).
__global__ __launch_bounds__(256) void roipool_fused(
    const float* __restrict__ feat, const int* __restrict__ rois,
    float* __restrict__ out)
{
    constexpr int C = 256, H = 64, W = 64;
    __shared__ float racc_lds[CPB * 64];   // per-wave row-accumulator
    __shared__ float pooled[CPB * NBINS];  // store staging (coalesced write)

    const int bx = blockIdx.x;
    const int n  = bx >> 6;                // roi index (128)
    const int c0 = (bx & 63) * CPB;        // channel group base

    const int tid  = threadIdx.x;
    const int lane = tid & 63;             // == x coordinate
    const int wave = tid >> 6;
    const int c    = c0 + wave;

    if (tid < CPB * NBINS) pooled[tid] = 0.0f;

    const int* r = rois + n * 5;
    const int b  = r[0];
    const int x1 = r[1];
    const int y1 = r[2];
    const int x2 = r[3];
    const int y2 = r[4];
    const int roi_h = y2 - y1 + 1;
    const int roi_w = x2 - x1 + 1;

    const float* plane = feat + ((size_t)(b * C + c)) * (H * W);

    __syncthreads();   // cover pooled[] zero-init

    for (int ph = 0; ph < OUT_H; ++ph) {
        int hs = (ph * roi_h) / OUT_H;
        int he = ((ph + 1) * roi_h) / OUT_H;
        hs = hs < roi_h - 1 ? hs : roi_h - 1;
        he = he < roi_h ? he : roi_h;
        const bool ph_valid = (he > hs);   // block-uniform

        if (ph_valid) {
            float racc = -INFINITY;
            for (int y = y1 + hs; y < y1 + he; ++y) {
                racc = fmaxf(racc, plane[y * W + lane]);  // coalesced 256B
            }
            racc_lds[wave * 64 + lane] = racc;
        }
        __syncthreads();

        if (ph_valid && tid < CPB * OUT_W) {
            const int pw = tid % OUT_W;
            const int cw = tid / OUT_W;
            int ws = (pw * roi_w) / OUT_W;
            int we = ((pw + 1) * roi_w) / OUT_W;
            ws = ws < roi_w - 1 ? ws : roi_w - 1;
            we = we < roi_w ? we : roi_w;
            if (we > ws) {
                float m = -INFINITY;
                const float* seg = &racc_lds[cw * 64 + x1];
                for (int x = ws; x < we; ++x) m = fmaxf(m, seg[x]);
                pooled[cw * NBINS + ph * OUT_W + pw] = m;
            }
        }
        __syncthreads();   // protect racc_lds reuse next ph
    }

    // out[n][c0..c0+3][ph][pw] is 196 contiguous floats
    if (tid < CPB * NBINS) {
        out[((size_t)(n * C + c0)) * NBINS + tid] = pooled[tid];
    }
}

extern "C" void kernel_launch(void* const* d_in, const int* in_sizes, int n_in,
                              void* d_out, int out_size, void* d_ws, size_t ws_size,
                              hipStream_t stream) {
    const float* feat = (const float*)d_in[0];
    const int*   rois = (const int*)d_in[1];
    float*       out  = (float*)d_out;

    const int N = in_sizes[1] / 5;        // 128 rois
    const int n_blocks = N * (256 / CPB); // 128 * 64 = 8192

    roipool_fused<<<n_blocks, 256, 0, stream>>>(feat, rois, out);
}

// Round 7
// 87.524 us; speedup vs baseline: 1.1231x; 1.1231x over previous
//
#include <hip/hip_runtime.h>
#include <math.h>

#define OUT_H 7
#define OUT_W 7
#define NBINS 49
#define LDS_STRIDE 65   // 64+1: kills 7-way bank aliasing across ph rows

// One WAVE per (n,c); zero __syncthreads in the kernel.
//   - lane == x: every window row is one coalesced 256B load; rows are
//     partitioned over the 7 ph bins, each loaded exactly once, all loads
//     independent (racc[7] in registers) -> deep pipelining, no barriers.
//   - column maxes via wave-private LDS (same-wave ds ordering).
//   - bin bounds: exact integer floor(k*roi/7) == (k*roi)/7 (validated R4/R6,
//     absmax 0 vs the f64 numpy reference).
//   - grid bx = n*64+cg: XCD = cg%8, so each XCD re-reads a fixed 2MB channel
//     subset that fits its 4MB L2.
__global__ __launch_bounds__(256) void roipool_wave(
    const float* __restrict__ feat, const int* __restrict__ rois,
    float* __restrict__ out)
{
    constexpr int C = 256, H = 64, W = 64;
    __shared__ float racc_lds[4][OUT_H * LDS_STRIDE];

    const int bx  = blockIdx.x;
    const int n   = bx >> 6;          // roi (128)
    const int cg  = bx & 63;          // channel group (4 ch)

    const int tid  = threadIdx.x;
    const int lane = tid & 63;        // == x
    const int wave = tid >> 6;
    const int c    = cg * 4 + wave;

    const int* r = rois + n * 5;
    const int b  = r[0];
    const int x1 = r[1];
    const int y1 = r[2];
    const int x2 = r[3];
    const int y2 = r[4];
    const int roi_h = y2 - y1 + 1;
    const int roi_w = x2 - x1 + 1;

    const float* plane = feat + ((size_t)(b * C + c)) * (H * W);

    float racc[OUT_H];
    #pragma unroll
    for (int ph = 0; ph < OUT_H; ++ph) racc[ph] = -INFINITY;

    // Rows partition over ph bins: single monotonic y sweep, each row loaded
    // once, all loads independent.
    int y = y1;
    #pragma unroll
    for (int ph = 0; ph < OUT_H; ++ph) {
        const int yend = y1 + ((ph + 1) * roi_h) / OUT_H;
        for (; y < yend; ++y) {
            racc[ph] = fmaxf(racc[ph], plane[y * W + lane]);  // coalesced 256B
        }
    }

    // Wave-private LDS round-trip for the cross-lane column reduction.
    #pragma unroll
    for (int ph = 0; ph < OUT_H; ++ph) {
        racc_lds[wave][ph * LDS_STRIDE + lane] = racc[ph];
    }

    if (lane < NBINS) {
        const int ph = lane / OUT_W;
        const int pw = lane - ph * OUT_W;

        int hs = (ph * roi_h) / OUT_H;
        int he = ((ph + 1) * roi_h) / OUT_H;
        int ws = (pw * roi_w) / OUT_W;
        int we = ((pw + 1) * roi_w) / OUT_W;

        float result = 0.0f;
        if (he > hs && we > ws) {
            float m = -INFINITY;
            const float* seg = &racc_lds[wave][ph * LDS_STRIDE + x1];
            for (int x = ws; x < we; ++x) m = fmaxf(m, seg[x]);
            result = m;
        }
        // out[n][c][ph][pw]: 49 contiguous floats per wave
        out[((size_t)(n * C + c)) * NBINS + lane] = result;
    }
}

extern "C" void kernel_launch(void* const* d_in, const int* in_sizes, int n_in,
                              void* d_out, int out_size, void* d_ws, size_t ws_size,
                              hipStream_t stream) {
    const float* feat = (const float*)d_in[0];
    const int*   rois = (const int*)d_in[1];
    float*       out  = (float*)d_out;

    const int N = in_sizes[1] / 5;     // 128 rois
    const int n_blocks = N * 64;       // 8192 blocks x 4 waves = 1 wave/(n,c)

    roipool_wave<<<n_blocks, 256, 0, stream>>>(feat, rois, out);
}

// Round 8
// 87.275 us; speedup vs baseline: 1.1263x; 1.0029x over previous
//
#include <hip/hip_runtime.h>
#include <math.h>

#define OUT_H 7
#define OUT_W 7
#define NBINS 49

// 4-row x 64-col chunk = 1024B DMA'd per global_load_lds issue; +16B pad
// between chunks so phase-2's 7-lanes-same-x gather spreads across banks.
#define CHUNK_FLOATS 260              // 256 data + 4 pad
#define MAX_CHUNKS 12                 // roi_h <= 48
#define WAVE_LDS_FLOATS (MAX_CHUNKS * CHUNK_FLOATS)  // 12480 B/wave

typedef __attribute__((address_space(3))) void lds_void_t;
typedef const __attribute__((address_space(1))) void gbl_void_t;

// One WAVE per (n,c), zero barriers. The poison fill between timed launches
// flushes L2+LLC, so loads are ~900-cyc HBM misses: the design goal is ONE
// latency exposure per wave (all row-chunk DMAs in flight simultaneously),
// instead of R7's serial load->fmax chain (26 exposures, ~33us).
// Bin bounds: exact integer floor(k*roi/7) == (k*roi)/7 (absmax 0 since R4).
__global__ __launch_bounds__(256) void roipool_dma(
    const float* __restrict__ feat, const int* __restrict__ rois,
    float* __restrict__ out)
{
    constexpr int C = 256, H = 64, W = 64;
    __shared__ float lds[4 * WAVE_LDS_FLOATS];   // 49920 B -> 3 blocks/CU

    const int bx   = blockIdx.x;
    const int n    = bx >> 6;          // roi (128)
    const int cg   = bx & 63;          // channel group; XCD = cg%8 (L2 affinity)
    const int tid  = threadIdx.x;
    const int lane = tid & 63;
    const int wave = tid >> 6;
    const int c    = cg * 4 + wave;

    const int* r = rois + n * 5;
    const int b  = r[0];
    const int x1 = r[1];
    const int y1 = r[2];
    const int x2 = r[3];
    const int y2 = r[4];
    const int roi_h = y2 - y1 + 1;
    const int roi_w = x2 - x1 + 1;

    const float* plane = feat + ((size_t)(b * C + c)) * (H * W);
    float* wlds = &lds[wave * WAVE_LDS_FLOATS];

    // ---- Phase 1: async DMA all window rows into LDS, all loads in flight.
    // lane -> (row-in-chunk l4, x-quad lq); HW scatters lane l to base+l*16,
    // which equals row-major (l4, lq) in a 4x64 chunk.
    const int l4 = lane >> 4;
    const int lq = lane & 15;
    const int nchunks = (roi_h + 3) >> 2;          // wave-uniform
    for (int k = 0; k < nchunks; ++k) {
        int y = y1 + 4 * k + l4;
        y = y < 63 ? y : 63;    // per-lane clamp; valid rows (dy<roi_h) never clamp
        const float* g = plane + y * W + lq * 4;
        __builtin_amdgcn_global_load_lds(
            (gbl_void_t*)g, (lds_void_t*)(wlds + k * CHUNK_FLOATS), 16, 0, 0);
    }
    __builtin_amdgcn_s_waitcnt(0);   // single wait for all DMAs (wave-private)

    // ---- Phase 2: 49 lanes gather their (ph,pw) bin from LDS.
    const int ph = lane / OUT_W;          // garbage for lane>=49, guarded below
    const int pw = lane - ph * OUT_W;

    int hs = (ph * roi_h) / OUT_H;
    int he = ((ph + 1) * roi_h) / OUT_H;
    hs = hs < roi_h - 1 ? hs : roi_h - 1;
    he = he < roi_h ? he : roi_h;
    int ws = (pw * roi_w) / OUT_W;
    int we = ((pw + 1) * roi_w) / OUT_W;
    ws = ws < roi_w - 1 ? ws : roi_w - 1;
    we = we < roi_w ? we : roi_w;

    float result = 0.0f;
    if (lane < NBINS && he > hs && we > ws) {
        float m = -INFINITY;
        for (int dy = hs; dy < he; ++dy) {
            const float* rowp = &wlds[(dy >> 2) * CHUNK_FLOATS + (dy & 3) * W + x1];
            for (int x = ws; x < we; ++x) {
                m = fmaxf(m, rowp[x]);
            }
        }
        result = m;
    }
    if (lane < NBINS) {
        // 49 contiguous floats per wave; block covers 196 consecutive
        out[((size_t)(n * C + c)) * NBINS + lane] = result;
    }
}

extern "C" void kernel_launch(void* const* d_in, const int* in_sizes, int n_in,
                              void* d_out, int out_size, void* d_ws, size_t ws_size,
                              hipStream_t stream) {
    const float* feat = (const float*)d_in[0];
    const int*   rois = (const int*)d_in[1];
    float*       out  = (float*)d_out;

    const int N = in_sizes[1] / 5;     // 128 rois
    const int n_blocks = N * 64;       // 1 wave per (n,c)

    roipool_dma<<<n_blocks, 256, 0, stream>>>(feat, rois, out);
}

// Round 9
// 77.748 us; speedup vs baseline: 1.2643x; 1.1225x over previous
//
#include <hip/hip_runtime.h>
#include <math.h>

#define OUT_H 7
#define OUT_W 7
#define NBINS 49

// One WAVE (64-thread block) per (n,c); lane == x. Design rule learned from
// R4-R8 (all ~30-44us): every dynamic-trip memory loop serializes at one
// outstanding op (~120cyc LDS / ~200-900cyc global each). So ALL memory
// accesses here are statically unrolled with index clamping (duplicates are
// harmless under max): phase 1 = 28 (+28 iff roi_h>28, uniform) global loads
// -> ONE vmcnt exposure; phase 2 = 8 ds_reads -> ONE lgkmcnt exposure.
// Tiny LDS (1.8KB) -> 32 waves/CU, so the short chains overlap 8-deep/SIMD.
// Bin bounds: exact integer floor(k*roi/7) == (k*roi)/7 (absmax 0 since R4).
// Grid bx = n*256+c: XCD = c%8 -> each XCD re-reads a fixed 2MB channel
// subset that fits its 4MB L2.
__global__ __launch_bounds__(64) void roipool_v9(
    const float* __restrict__ feat, const int* __restrict__ rois,
    float* __restrict__ out)
{
    constexpr int C = 256, H = 64, W = 64;
    __shared__ float racc_lds[OUT_H][W + 1];   // +1 pad: phase-2 bank spread

    const int bx   = blockIdx.x;
    const int n    = bx >> 8;          // roi (128)
    const int c    = bx & 255;         // channel
    const int lane = threadIdx.x;      // == x

    const int* r = rois + n * 5;
    const int b  = r[0];
    const int x1 = r[1];
    const int y1 = r[2];
    const int roi_w = r[3] - x1 + 1;
    const int roi_h = r[4] - y1 + 1;

    const float* plane = feat + ((size_t)(b * C + c)) * (H * W);

    int hb[OUT_H + 1];                 // statically indexed -> registers
#pragma unroll
    for (int k = 0; k <= OUT_H; ++k) hb[k] = (k * roi_h) / OUT_H;

    float racc[OUT_H];
    {
        float v[OUT_H][4];
#pragma unroll
        for (int ph = 0; ph < OUT_H; ++ph) {
            const int yb = y1 + hb[ph];
            int yl = y1 + hb[ph + 1] - 1;   // last row of bin
            yl = yl > yb ? yl : yb;         // empty-bin guard (stays in-image)
#pragma unroll
            for (int j = 0; j < 4; ++j) {
                int y = yb + j;
                y = y < yl ? y : yl;        // clamp: duplicate rows, same bin
                v[ph][j] = plane[y * W + lane];   // coalesced 256B
            }
        }
#pragma unroll
        for (int ph = 0; ph < OUT_H; ++ph)
            racc[ph] = fmaxf(fmaxf(v[ph][0], v[ph][1]),
                             fmaxf(v[ph][2], v[ph][3]));
    }
    if (roi_h > 28) {   // uniform: only then can a bin exceed 4 rows (max 7)
        float v[OUT_H][4];
#pragma unroll
        for (int ph = 0; ph < OUT_H; ++ph) {
            const int yb = y1 + hb[ph];
            const int yl = y1 + hb[ph + 1] - 1;  // cnt>=4 here, yl>=yb+3
#pragma unroll
            for (int j = 0; j < 4; ++j) {
                int y = yb + 4 + j;
                y = y < yl ? y : yl;
                v[ph][j] = plane[y * W + lane];
            }
        }
#pragma unroll
        for (int ph = 0; ph < OUT_H; ++ph)
            racc[ph] = fmaxf(racc[ph],
                             fmaxf(fmaxf(v[ph][0], v[ph][1]),
                                   fmaxf(v[ph][2], v[ph][3])));
    }

    // Wave-private LDS round-trip (single-wave block: no barrier needed).
#pragma unroll
    for (int ph = 0; ph < OUT_H; ++ph) racc_lds[ph][lane] = racc[ph];

    if (lane < NBINS) {
        const int ph = lane / OUT_W;
        const int pw = lane - ph * OUT_W;

        const int hsL = (ph * roi_h) / OUT_H;        // per-lane validity
        const int heL = ((ph + 1) * roi_h) / OUT_H;
        const int ws  = (pw * roi_w) / OUT_W;
        const int we  = ((pw + 1) * roi_w) / OUT_W;

        const int xs = x1 + ws;
        int xl = x1 + we - 1;
        xl = xl > xs ? xl : xs;          // empty-bin guard

        float g[8];                      // max bin width = ceil(48/7) = 7 <= 8
#pragma unroll
        for (int j = 0; j < 8; ++j) {
            int x = xs + j;
            x = x < xl ? x : xl;         // clamp: duplicates harmless
            g[j] = racc_lds[ph][x];
        }
        float m = fmaxf(fmaxf(fmaxf(g[0], g[1]), fmaxf(g[2], g[3])),
                        fmaxf(fmaxf(g[4], g[5]), fmaxf(g[6], g[7])));

        const bool valid = (heL > hsL) && (we > ws);
        // out[n][c][ph][pw]: 49 contiguous floats per wave
        out[((size_t)(n * C + c)) * NBINS + lane] = valid ? m : 0.0f;
    }
}

extern "C" void kernel_launch(void* const* d_in, const int* in_sizes, int n_in,
                              void* d_out, int out_size, void* d_ws, size_t ws_size,
                              hipStream_t stream) {
    const float* feat = (const float*)d_in[0];
    const int*   rois = (const int*)d_in[1];
    float*       out  = (float*)d_out;

    const int N = in_sizes[1] / 5;     // 128 rois
    const int n_blocks = N * 256;      // one wave per (n,c)

    roipool_v9<<<n_blocks, 64, 0, stream>>>(feat, rois, out);
}